// Round 9
// baseline (159.278 us; speedup 1.0000x reference)
//
#include <hip/hip_runtime.h>
#include <hip/hip_bf16.h>

// features (16384,128) fp32; B=8192; D=128. TEMP=1 -> t2=1; BETA=0.5; ALPHA=0.5; GAMMA=0.5.
// out = positive_loss + nl_a + nl_b + 0.5*(s_a + s_b), scalar fp32.
//
// Round-8 lesson: LDS-staged neg_kernel was latency/structure-bound (VALU work removal
// changed nothing; no pipe >50%). xbf is 4MB = L2-resident -> drop LDS staging entirely
// (guide common-mistake #7). Both MFMA operands are rows of xbf with identical 16B/lane
// fragment layout, loaded directly from global/L2. No barriers until final 64B reduce.
//
//  1) prep_pos_kernel (256 blocks): fp32->bf16 + row |x|^2 + pos partials + zero negacc
//  2) neg_kernel (2080x2 blocks, no LDS tiles): upper-triangle 128x128 MFMA fused
//     sim-reduction, weight 2 off-diagonal, Taylor exp(s/2) epilogue
//  3) finish_kernel: sum 64 negacc slots + 256 prep partials -> d_out

typedef __attribute__((ext_vector_type(8))) short short8;
typedef __attribute__((ext_vector_type(4))) float float4v;

#define NROWS 16384
#define BHALF 8192
#define D 128
#define NT 64            // 8192/128 tiles per dim
#define NPAIRS 2080      // NT*(NT+1)/2
#define NACC 64
#define NPART 256

__device__ __forceinline__ unsigned short f2bf(float x) {
    unsigned int u = __float_as_uint(x);
    u += 0x7fffu + ((u >> 16) & 1u);   // RNE
    return (unsigned short)(u >> 16);
}

// ---- Kernel 1: convert + row norms + positive loss (2048 waves) ----
__global__ __launch_bounds__(512)
void prep_pos_kernel(const float* __restrict__ f,
                     unsigned short* __restrict__ xbf,
                     float* __restrict__ xx,
                     float* __restrict__ part,
                     float* __restrict__ negacc) {
    __shared__ float red[8];
    const int wave = threadIdx.x >> 6, lane = threadIdx.x & 63;
    const int gw = blockIdx.x * 8 + wave;   // 0..2047
    float posAcc = 0.0f;

    #pragma unroll
    for (int p = 0; p < 4; ++p) {
        const int i = gw + p * 2048;        // pair index 0..8191
        const float2 a = *reinterpret_cast<const float2*>(f + (size_t)i * D + lane * 2);
        const float2 b = *reinterpret_cast<const float2*>(f + (size_t)(i + BHALF) * D + lane * 2);
        ushort2 sa2, sb2;
        sa2.x = f2bf(a.x); sa2.y = f2bf(a.y);
        sb2.x = f2bf(b.x); sb2.y = f2bf(b.y);
        *reinterpret_cast<ushort2*>(xbf + (size_t)i * D + lane * 2) = sa2;
        *reinterpret_cast<ushort2*>(xbf + (size_t)(i + BHALF) * D + lane * 2) = sb2;
        float sa = a.x * a.x + a.y * a.y;
        float sb = b.x * b.x + b.y * b.y;
        float dx = a.x - b.x, dy = a.y - b.y;
        float sp = dx * dx + dy * dy;
        #pragma unroll
        for (int off = 32; off; off >>= 1) {
            sa += __shfl_down(sa, off, 64);
            sb += __shfl_down(sb, off, 64);
            sp += __shfl_down(sp, off, 64);
        }
        if (lane == 0) {
            xx[i] = sa;
            xx[i + BHALF] = sb;
            float ps = 1.0f / (sp + 1.0f);
            posAcc += (ps - 10.0f) * (ps - 10.0f) - ps;   // -2*ALPHA*ps = -ps
        }
    }
    if (lane == 0) red[wave] = posAcc;
    if (blockIdx.x == 0 && threadIdx.x < NACC) negacc[threadIdx.x] = 0.0f;
    __syncthreads();
    if (threadIdx.x == 0) {
        float s = 0.0f;
        #pragma unroll
        for (int w = 0; w < 8; ++w) s += red[w];
        part[blockIdx.x] = s;                 // raw sum; /B applied in finish
    }
}

// ---- Kernel 2: fused symmetric sim-reduction, operands direct from L2 ----
// grid = (NPAIRS, 2): blockIdx.y = matrix (0=a,1=b); blockIdx.x = upper-tri pair.
// 512 threads = 8 waves (4 row-waves x 2 col-waves), each wave: 32x64 output.
// No LDS operand tiles, no stage barrier: xbf (4MB) is L2-resident; both MFMA
// operands are rows of xbf, fragment = 16B contiguous per lane.
__global__ __launch_bounds__(512, 4)
void neg_kernel(const unsigned short* __restrict__ xbf,
                const float* __restrict__ xx,
                float* __restrict__ negacc) {
    __shared__ float red[16];

    const int t = threadIdx.x;
    const int mat = blockIdx.y;
    const int moff = mat * BHALF;

    // decode upper-triangular pair index -> (tbi, tbj), tbi <= tbj
    int rem = blockIdx.x, bi = 0;
    while (rem >= NT - bi) { rem -= NT - bi; ++bi; }
    const int tbi = bi, tbj = bi + rem;

    const int wave = t >> 6, lane = t & 63;
    const int wr = wave >> 1, wc = wave & 1;      // 4 x 2 wave grid
    const int l15 = lane & 15, g = lane >> 4;

    // per-lane fragment row bases (element offsets into xbf)
    const unsigned short* Aubase = xbf + ((size_t)(moff + tbi * 128 + wr * 32 + l15) * D + g * 8);
    const unsigned short* Bubase = xbf + ((size_t)(moff + tbj * 128 + wc * 64 + l15) * D + g * 8);

    float4v accv[2][4] = {};

    #pragma unroll
    for (int kk = 0; kk < 4; ++kk) {
        short8 a[2], b[4];
        #pragma unroll
        for (int mi = 0; mi < 2; ++mi)
            a[mi] = *reinterpret_cast<const short8*>(Aubase + mi * 16 * D + kk * 32);
        #pragma unroll
        for (int ni = 0; ni < 4; ++ni)
            b[ni] = *reinterpret_cast<const short8*>(Bubase + ni * 16 * D + kk * 32);
        #pragma unroll
        for (int mi = 0; mi < 2; ++mi)
            #pragma unroll
            for (int ni = 0; ni < 4; ++ni)
                accv[mi][ni] = __builtin_amdgcn_mfma_f32_16x16x32_bf16(a[mi], b[ni], accv[mi][ni], 0, 0, 0);
    }

    // ---- fused epilogue (cubic Taylor of exp(s/2), s in [0,1]) ----
    const bool diag = (tbi == tbj);
    const int rbase = tbi * 128 + wr * 32;   // local (per-matrix) row base
    const int cbase = tbj * 128 + wc * 64;

    float xr1[8], xc[4];
    #pragma unroll
    for (int mi = 0; mi < 2; ++mi)
        #pragma unroll
        for (int r = 0; r < 4; ++r)
            xr1[mi * 4 + r] = xx[moff + rbase + mi * 16 + g * 4 + r] + 1.0f;  // fold +1 of d+1
    #pragma unroll
    for (int ni = 0; ni < 4; ++ni)
        xc[ni] = xx[moff + cbase + ni * 16 + l15];

    float aS0 = 0.0f, aS1 = 0.0f, aN0 = 0.0f, aN1 = 0.0f;
    #pragma unroll
    for (int mi = 0; mi < 2; ++mi) {
        #pragma unroll
        for (int ni = 0; ni < 4; ++ni) {
            #pragma unroll
            for (int r = 0; r < 4; ++r) {
                const float dot = accv[mi][ni][r];
                // d+1 = xr+xc-2dot+1 ; max(d,0)+1 = max(d+1, 1)
                float t1 = xr1[mi * 4 + r] + xc[ni];
                float m = fmaxf(fmaf(dot, -2.0f, t1), 1.0f);
                float s = __builtin_amdgcn_rcpf(m);
                if (diag) {
                    const int row = rbase + mi * 16 + g * 4 + r;
                    const int col = cbase + ni * 16 + l15;
                    if (row == col) s = 0.0f;
                }
                // exp(0.5s) ~= 1 + s/2 + s^2/8 + s^3/48  (|err| <= 0.0026 s^4)
                float p = fmaf(s, 0.02083333333f, 0.125f);
                p = fmaf(s, p, 0.5f);
                p = fmaf(s, p, 1.0f);
                if (r & 1) { aS1 += s; aN1 = fmaf(p, s, aN1); }
                else       { aS0 += s; aN0 = fmaf(p, s, aN0); }
            }
        }
    }
    float aS = aS0 + aS1, aN = aN0 + aN1;

    // ---- block reduction ----
    #pragma unroll
    for (int off = 32; off; off >>= 1) {
        aS += __shfl_down(aS, off, 64);
        aN += __shfl_down(aN, off, 64);
    }
    if (lane == 0) { red[wave * 2] = aS; red[wave * 2 + 1] = aN; }
    __syncthreads();
    if (t == 0) {
        float S = 0.0f, N = 0.0f;
        #pragma unroll
        for (int w = 0; w < 8; ++w) { S += red[w * 2]; N += red[w * 2 + 1]; }
        const float w = diag ? 1.0f : 2.0f;
        // neg_loss contribution: N/B ; regularization: GAMMA * S
        atomicAdd(&negacc[(blockIdx.x * 2 + blockIdx.y) & (NACC - 1)],
                  w * (N * (1.0f / (float)BHALF) + 0.5f * S));
    }
}

// ---- Kernel 3: final sum (64 neg slots + 256 prep partials) ----
__global__ void finish_kernel(const float* __restrict__ negacc,
                              const float* __restrict__ part,
                              float* __restrict__ out) {
    const int lane = threadIdx.x & 63;
    float v = negacc[lane];
    float pp = part[lane] + part[lane + 64] + part[lane + 128] + part[lane + 192];
    v = fmaf(pp, 1.0f / (float)BHALF, v);
    #pragma unroll
    for (int off = 32; off; off >>= 1) v += __shfl_down(v, off, 64);
    if (lane == 0) out[0] = v;
}

extern "C" void kernel_launch(void* const* d_in, const int* in_sizes, int n_in,
                              void* d_out, int out_size, void* d_ws, size_t ws_size,
                              hipStream_t stream) {
    const float* f = (const float*)d_in[0];
    float* out = (float*)d_out;
    unsigned short* xbf = (unsigned short*)d_ws;
    float* xx = (float*)((char*)d_ws + (size_t)NROWS * D * sizeof(unsigned short));
    float* negacc = xx + NROWS;
    float* part = negacc + NACC;

    prep_pos_kernel<<<NPART, 512, 0, stream>>>(f, xbf, xx, part, negacc);
    neg_kernel<<<dim3(NPAIRS, 2), 512, 0, stream>>>(xbf, xx, negacc);
    finish_kernel<<<1, 64, 0, stream>>>(negacc, part, out);
}

// Round 10
// 133.287 us; speedup vs baseline: 1.1950x; 1.1950x over previous
//
#include <hip/hip_runtime.h>
#include <hip/hip_bf16.h>

// features (16384,128) fp32; B=8192; D=128. TEMP=1 -> t2=1; BETA=0.5; ALPHA=0.5; GAMMA=0.5.
// out = positive_loss + nl_a + nl_b + 0.5*(s_a + s_b), scalar fp32.
//
// Round-9 lesson: full direct-L2 operands = latency-serialized (VALU 22%, 108us).
// Round-8 lesson: 64KB both-tile LDS staging = 2 blocks/CU, barrier-coupled (47% VALU, 54us).
// This round: stage ONLY B (higher cross-wave reuse, x4) in 16KB LDS; A direct from L2
// (reused x2 per wave, latency hidden by 4 blocks/CU = 32 waves/CU full occupancy).
// Tiles: 128(i) x 64(j); 8 waves = 4(i) x 2(j); per-wave 32x32 output, acc = 16 VGPR.
// Upper triangle: enumerate (ri, cj) with cj >= 2*ri; straddle tiles (cj>>1==ri) use
// per-element C>R predicate; weight uniformly 2.

typedef __attribute__((ext_vector_type(8))) short short8;
typedef __attribute__((ext_vector_type(4))) float float4v;

#define NROWS 16384
#define BHALF 8192
#define D 128
#define NRT 64           // 8192/128 row-tiles
#define NCT 128          // 8192/64  col-tiles
#define NPAIRS 4160      // sum_{ri} (128 - 2*ri) = 4160
#define NACC 64
#define NPART 256

__device__ __forceinline__ unsigned short f2bf(float x) {
    unsigned int u = __float_as_uint(x);
    u += 0x7fffu + ((u >> 16) & 1u);   // RNE
    return (unsigned short)(u >> 16);
}

// ---- Kernel 1: convert + row norms + positive loss (2048 waves) ----
__global__ __launch_bounds__(512)
void prep_pos_kernel(const float* __restrict__ f,
                     unsigned short* __restrict__ xbf,
                     float* __restrict__ xx,
                     float* __restrict__ part,
                     float* __restrict__ negacc) {
    __shared__ float red[8];
    const int wave = threadIdx.x >> 6, lane = threadIdx.x & 63;
    const int gw = blockIdx.x * 8 + wave;   // 0..2047
    float posAcc = 0.0f;

    #pragma unroll
    for (int p = 0; p < 4; ++p) {
        const int i = gw + p * 2048;        // pair index 0..8191
        const float2 a = *reinterpret_cast<const float2*>(f + (size_t)i * D + lane * 2);
        const float2 b = *reinterpret_cast<const float2*>(f + (size_t)(i + BHALF) * D + lane * 2);
        ushort2 sa2, sb2;
        sa2.x = f2bf(a.x); sa2.y = f2bf(a.y);
        sb2.x = f2bf(b.x); sb2.y = f2bf(b.y);
        *reinterpret_cast<ushort2*>(xbf + (size_t)i * D + lane * 2) = sa2;
        *reinterpret_cast<ushort2*>(xbf + (size_t)(i + BHALF) * D + lane * 2) = sb2;
        float sa = a.x * a.x + a.y * a.y;
        float sb = b.x * b.x + b.y * b.y;
        float dx = a.x - b.x, dy = a.y - b.y;
        float sp = dx * dx + dy * dy;
        #pragma unroll
        for (int off = 32; off; off >>= 1) {
            sa += __shfl_down(sa, off, 64);
            sb += __shfl_down(sb, off, 64);
            sp += __shfl_down(sp, off, 64);
        }
        if (lane == 0) {
            xx[i] = sa;
            xx[i + BHALF] = sb;
            float ps = 1.0f / (sp + 1.0f);
            posAcc += (ps - 10.0f) * (ps - 10.0f) - ps;   // -2*ALPHA*ps = -ps
        }
    }
    if (lane == 0) red[wave] = posAcc;
    if (blockIdx.x == 0 && threadIdx.x < NACC) negacc[threadIdx.x] = 0.0f;
    __syncthreads();
    if (threadIdx.x == 0) {
        float s = 0.0f;
        #pragma unroll
        for (int w = 0; w < 8; ++w) s += red[w];
        part[blockIdx.x] = s;                 // raw sum; /B applied in finish
    }
}

// ---- Kernel 2: fused sim-reduction, 128x64 tiles, B in LDS, A direct L2 ----
// grid = (NPAIRS, 2). 512 threads = 8 waves (4 row x 2 col); per-wave 32x32 out.
__global__ __launch_bounds__(512, 8)
void neg_kernel(const unsigned short* __restrict__ xbf,
                const float* __restrict__ xx,
                float* __restrict__ negacc) {
    __shared__ unsigned short lB[64 * 128];  // 16 KiB, XOR-swizzled 16B units
    __shared__ float red[16];

    const int t = threadIdx.x;
    const int mat = blockIdx.y;
    const int moff = mat * BHALF;

    // decode pair index -> (ri, cj) with cj >= 2*ri
    int rem = blockIdx.x, ri = 0;
    while (rem >= NCT - 2 * ri) { rem -= NCT - 2 * ri; ++ri; }
    const int cj = 2 * ri + rem;
    const bool straddle = ((cj >> 1) == ri);

    const int wave = t >> 6, lane = t & 63;
    const int wr = wave >> 1, wc = wave & 1;      // 4 x 2 wave grid
    const int l15 = lane & 15, g = lane >> 4;

    // ---- stage B tile (64 rows x 128 cols bf16 = 16KB) via global_load_lds ----
    // LDS dest linear; XOR swizzle on GLOBAL source (involution) recovered by swizzled reads.
    {
        const char* gbase = (const char*)(xbf + (size_t)(moff + cj * 64) * D);
        #pragma unroll
        for (int p = 0; p < 2; ++p) {
            const int c = p * 512 + t;            // 16B-unit index 0..1023
            const int row = c >> 4, col16 = c & 15;
            const int gb = row * 256 + ((col16 * 16) ^ ((row & 7) << 4));
            const unsigned ldsoff = (unsigned)(p * 512 + wave * 64) * 16;  // wave-uniform
            __builtin_amdgcn_global_load_lds(
                (const __attribute__((address_space(1))) unsigned int*)(gbase + gb),
                (__attribute__((address_space(3))) unsigned int*)((char*)lB + ldsoff),
                16, 0, 0);
        }
    }

    // per-lane A fragment base (direct from global/L2; reused x2 MFMAs each)
    const unsigned short* Aubase =
        xbf + ((size_t)(moff + ri * 128 + wr * 32 + l15) * D + g * 8);

    __syncthreads();

    float4v accv[2][2] = {};

    #pragma unroll
    for (int kk = 0; kk < 4; ++kk) {
        short8 a[2], b[2];
        #pragma unroll
        for (int mi = 0; mi < 2; ++mi)
            a[mi] = *reinterpret_cast<const short8*>(Aubase + mi * 16 * D + kk * 32);
        #pragma unroll
        for (int nj = 0; nj < 2; ++nj) {
            const int trow = wc * 32 + nj * 16 + l15;
            const int boff = (kk * 64 + g * 16) ^ ((trow & 7) << 4);
            b[nj] = *reinterpret_cast<short8*>(reinterpret_cast<char*>(lB) + trow * 256 + boff);
        }
        #pragma unroll
        for (int mi = 0; mi < 2; ++mi)
            #pragma unroll
            for (int nj = 0; nj < 2; ++nj)
                accv[mi][nj] = __builtin_amdgcn_mfma_f32_16x16x32_bf16(a[mi], b[nj], accv[mi][nj], 0, 0, 0);
    }

    // ---- fused epilogue (cubic Taylor of exp(s/2), s in [0,1]) ----
    const int rbase = ri * 128 + wr * 32;    // local (per-matrix) row base
    const int cbase = cj * 64 + wc * 32;     // local col base

    float xr1[8], xc[2];
    #pragma unroll
    for (int mi = 0; mi < 2; ++mi)
        #pragma unroll
        for (int r = 0; r < 4; ++r)
            xr1[mi * 4 + r] = xx[moff + rbase + mi * 16 + g * 4 + r] + 1.0f;  // fold +1 of d+1
    #pragma unroll
    for (int nj = 0; nj < 2; ++nj)
        xc[nj] = xx[moff + cbase + nj * 16 + l15];

    float aS0 = 0.0f, aS1 = 0.0f, aN0 = 0.0f, aN1 = 0.0f;
    #pragma unroll
    for (int mi = 0; mi < 2; ++mi) {
        #pragma unroll
        for (int nj = 0; nj < 2; ++nj) {
            #pragma unroll
            for (int r = 0; r < 4; ++r) {
                const float dot = accv[mi][nj][r];
                // max(d,0)+1 = max(xr+xc-2dot+1, 1)
                float t1 = xr1[mi * 4 + r] + xc[nj];
                float m = fmaxf(fmaf(dot, -2.0f, t1), 1.0f);
                float s = __builtin_amdgcn_rcpf(m);
                if (straddle) {
                    const int row = rbase + mi * 16 + g * 4 + r;
                    const int col = cbase + nj * 16 + l15;
                    if (col <= row) s = 0.0f;   // strictly-upper only; weight 2 applied below
                }
                // exp(0.5s) ~= 1 + s/2 + s^2/8 + s^3/48  (|err| <= 0.0026 s^4)
                float p = fmaf(s, 0.02083333333f, 0.125f);
                p = fmaf(s, p, 0.5f);
                p = fmaf(s, p, 1.0f);
                if (r & 1) { aS1 += s; aN1 = fmaf(p, s, aN1); }
                else       { aS0 += s; aN0 = fmaf(p, s, aN0); }
            }
        }
    }
    float aS = aS0 + aS1, aN = aN0 + aN1;

    // ---- block reduction ----
    #pragma unroll
    for (int off = 32; off; off >>= 1) {
        aS += __shfl_down(aS, off, 64);
        aN += __shfl_down(aN, off, 64);
    }
    if (lane == 0) { red[wave * 2] = aS; red[wave * 2 + 1] = aN; }
    __syncthreads();
    if (t == 0) {
        float S = 0.0f, N = 0.0f;
        #pragma unroll
        for (int w = 0; w < 8; ++w) { S += red[w * 2]; N += red[w * 2 + 1]; }
        // every counted element is strictly-upper (or full off-diag tile): weight 2.
        // contribution = 2*(N/B + GAMMA*S) with GAMMA=0.5 -> 2*N/B + S
        atomicAdd(&negacc[(blockIdx.x * 2 + blockIdx.y) & (NACC - 1)],
                  fmaf(N, 2.0f / (float)BHALF, S));
    }
}

// ---- Kernel 3: final sum (64 neg slots + 256 prep partials) ----
__global__ void finish_kernel(const float* __restrict__ negacc,
                              const float* __restrict__ part,
                              float* __restrict__ out) {
    const int lane = threadIdx.x & 63;
    float v = negacc[lane];
    float pp = part[lane] + part[lane + 64] + part[lane + 128] + part[lane + 192];
    v = fmaf(pp, 1.0f / (float)BHALF, v);
    #pragma unroll
    for (int off = 32; off; off >>= 1) v += __shfl_down(v, off, 64);
    if (lane == 0) out[0] = v;
}

extern "C" void kernel_launch(void* const* d_in, const int* in_sizes, int n_in,
                              void* d_out, int out_size, void* d_ws, size_t ws_size,
                              hipStream_t stream) {
    const float* f = (const float*)d_in[0];
    float* out = (float*)d_out;
    unsigned short* xbf = (unsigned short*)d_ws;
    float* xx = (float*)((char*)d_ws + (size_t)NROWS * D * sizeof(unsigned short));
    float* negacc = xx + NROWS;
    float* part = negacc + NACC;

    prep_pos_kernel<<<NPART, 512, 0, stream>>>(f, xbf, xx, part, negacc);
    neg_kernel<<<dim3(NPAIRS, 2), 512, 0, stream>>>(xbf, xx, negacc);
    finish_kernel<<<1, 64, 0, stream>>>(negacc, part, out);
}

// Round 12
// 122.066 us; speedup vs baseline: 1.3048x; 1.0919x over previous
//
#include <hip/hip_runtime.h>
#include <hip/hip_bf16.h>

// features (16384,128) fp32; B=8192; D=128. TEMP=1 -> t2=1; BETA=0.5; ALPHA=0.5; GAMMA=0.5.
// out = positive_loss + nl_a + nl_b + 0.5*(s_a + s_b), scalar fp32.
//
// Ladder so far (neg_kernel): R8 both-tiles-LDS 64KB, 2blk/CU = 54.3us (VALU 47%);
// R9 no-LDS = 108us (latency-serialized); R10 B-LDS + half tiles = 81.7us (2x blocks,
// per-block fixed costs dominate). This round: B-only LDS (32KB) at FULL 128x128 tile
// (2080x2 grid, same as R8) -> 4 blk/CU, 32 waves/CU, half the ds_read + stage bytes.
// A operand per-lane direct from global/L2 (reuse x2, hidden by TLP while B stages).

typedef __attribute__((ext_vector_type(8))) short short8;
typedef __attribute__((ext_vector_type(4))) float float4v;

#define NROWS 16384
#define BHALF 8192
#define D 128
#define NT 64            // 8192/128 tiles per dim
#define NPAIRS 2080      // NT*(NT+1)/2
#define NACC 64
#define NPART 256

__device__ __forceinline__ unsigned short f2bf(float x) {
    unsigned int u = __float_as_uint(x);
    u += 0x7fffu + ((u >> 16) & 1u);   // RNE
    return (unsigned short)(u >> 16);
}

// ---- Kernel 1: convert + row norms + positive loss (2048 waves) ----
__global__ __launch_bounds__(512)
void prep_pos_kernel(const float* __restrict__ f,
                     unsigned short* __restrict__ xbf,
                     float* __restrict__ xx,
                     float* __restrict__ part,
                     float* __restrict__ negacc) {
    __shared__ float red[8];
    const int wave = threadIdx.x >> 6, lane = threadIdx.x & 63;
    const int gw = blockIdx.x * 8 + wave;   // 0..2047
    float posAcc = 0.0f;

    #pragma unroll
    for (int p = 0; p < 4; ++p) {
        const int i = gw + p * 2048;        // pair index 0..8191
        const float2 a = *reinterpret_cast<const float2*>(f + (size_t)i * D + lane * 2);
        const float2 b = *reinterpret_cast<const float2*>(f + (size_t)(i + BHALF) * D + lane * 2);
        ushort2 sa2, sb2;
        sa2.x = f2bf(a.x); sa2.y = f2bf(a.y);
        sb2.x = f2bf(b.x); sb2.y = f2bf(b.y);
        *reinterpret_cast<ushort2*>(xbf + (size_t)i * D + lane * 2) = sa2;
        *reinterpret_cast<ushort2*>(xbf + (size_t)(i + BHALF) * D + lane * 2) = sb2;
        float sa = a.x * a.x + a.y * a.y;
        float sb = b.x * b.x + b.y * b.y;
        float dx = a.x - b.x, dy = a.y - b.y;
        float sp = dx * dx + dy * dy;
        #pragma unroll
        for (int off = 32; off; off >>= 1) {
            sa += __shfl_down(sa, off, 64);
            sb += __shfl_down(sb, off, 64);
            sp += __shfl_down(sp, off, 64);
        }
        if (lane == 0) {
            xx[i] = sa;
            xx[i + BHALF] = sb;
            float ps = 1.0f / (sp + 1.0f);
            posAcc += (ps - 10.0f) * (ps - 10.0f) - ps;   // -2*ALPHA*ps = -ps
        }
    }
    if (lane == 0) red[wave] = posAcc;
    if (blockIdx.x == 0 && threadIdx.x < NACC) negacc[threadIdx.x] = 0.0f;
    __syncthreads();
    if (threadIdx.x == 0) {
        float s = 0.0f;
        #pragma unroll
        for (int w = 0; w < 8; ++w) s += red[w];
        part[blockIdx.x] = s;                 // raw sum; /B applied in finish
    }
}

// ---- Kernel 2: fused symmetric sim-reduction, 128x128 tiles, B-only LDS ----
// grid = (NPAIRS, 2): blockIdx.y = matrix (0=a,1=b); blockIdx.x = upper-tri pair.
// 512 threads = 8 waves (4 row x 2 col); per-wave 32x64 output, acc = 32 VGPR.
__global__ __launch_bounds__(512, 8)
void neg_kernel(const unsigned short* __restrict__ xbf,
                const float* __restrict__ xx,
                float* __restrict__ negacc) {
    __shared__ unsigned short lB[128 * 128];  // 32 KiB, XOR-swizzled 16B units
    __shared__ float red[16];

    const int t = threadIdx.x;
    const int mat = blockIdx.y;
    const int moff = mat * BHALF;

    // decode upper-triangular pair index -> (tbi, tbj), tbi <= tbj
    int rem = blockIdx.x, bi = 0;
    while (rem >= NT - bi) { rem -= NT - bi; ++bi; }
    const int tbi = bi, tbj = bi + rem;

    const int wave = t >> 6, lane = t & 63;
    const int wr = wave >> 1, wc = wave & 1;      // 4 x 2 wave grid
    const int l15 = lane & 15, g = lane >> 4;

    // ---- stage B tile (tbj: 128 rows x 128 cols bf16 = 32KB) via global_load_lds ----
    // LDS dest linear; XOR swizzle applied to GLOBAL source (involution), recovered
    // by swizzled reads below (rule #21).
    {
        const char* gbase = (const char*)(xbf + (size_t)(moff + tbj * 128) * D);
        #pragma unroll
        for (int p = 0; p < 4; ++p) {
            const int c = p * 512 + t;            // 16B-unit index 0..2047
            const int row = c >> 4, col16 = c & 15;
            const int gb = row * 256 + ((col16 * 16) ^ ((row & 7) << 4));
            const unsigned ldsoff = (unsigned)(p * 512 + wave * 64) * 16;  // wave-uniform
            __builtin_amdgcn_global_load_lds(
                (const __attribute__((address_space(1))) unsigned int*)(gbase + gb),
                (__attribute__((address_space(3))) unsigned int*)((char*)lB + ldsoff),
                16, 0, 0);
        }
    }

    // per-lane A fragment base (direct from global/L2; each fragment reused x4 nj)
    const unsigned short* Aubase =
        xbf + ((size_t)(moff + tbi * 128 + wr * 32 + l15) * D + g * 8);

    __syncthreads();

    float4v accv[2][4] = {};

    #pragma unroll
    for (int kk = 0; kk < 4; ++kk) {
        short8 a[2], b[4];
        #pragma unroll
        for (int mi = 0; mi < 2; ++mi)
            a[mi] = *reinterpret_cast<const short8*>(Aubase + mi * 16 * D + kk * 32);
        #pragma unroll
        for (int ni = 0; ni < 4; ++ni) {
            const int trow = wc * 64 + ni * 16 + l15;
            const int boff = (kk * 64 + g * 16) ^ ((trow & 7) << 4);
            b[ni] = *reinterpret_cast<short8*>(reinterpret_cast<char*>(lB) + trow * 256 + boff);
        }
        #pragma unroll
        for (int mi = 0; mi < 2; ++mi)
            #pragma unroll
            for (int ni = 0; ni < 4; ++ni)
                accv[mi][ni] = __builtin_amdgcn_mfma_f32_16x16x32_bf16(a[mi], b[ni], accv[mi][ni], 0, 0, 0);
    }

    // ---- fused epilogue (cubic Taylor of exp(s/2), s in [0,1]) ----
    const bool diag = (tbi == tbj);
    const int rbase = tbi * 128 + wr * 32;   // local (per-matrix) row base
    const int cbase = tbj * 128 + wc * 64;

    float xr1[8], xc[4];
    #pragma unroll
    for (int mi = 0; mi < 2; ++mi)
        #pragma unroll
        for (int r = 0; r < 4; ++r)
            xr1[mi * 4 + r] = xx[moff + rbase + mi * 16 + g * 4 + r] + 1.0f;  // fold +1 of d+1
    #pragma unroll
    for (int ni = 0; ni < 4; ++ni)
        xc[ni] = xx[moff + cbase + ni * 16 + l15];

    float aS0 = 0.0f, aS1 = 0.0f, aN0 = 0.0f, aN1 = 0.0f;
    #pragma unroll
    for (int mi = 0; mi < 2; ++mi) {
        #pragma unroll
        for (int ni = 0; ni < 4; ++ni) {
            #pragma unroll
            for (int r = 0; r < 4; ++r) {
                const float dot = accv[mi][ni][r];
                // max(d,0)+1 = max(xr+xc-2dot+1, 1)
                float t1 = xr1[mi * 4 + r] + xc[ni];
                float m = fmaxf(fmaf(dot, -2.0f, t1), 1.0f);
                float s = __builtin_amdgcn_rcpf(m);
                if (diag) {
                    const int row = rbase + mi * 16 + g * 4 + r;
                    const int col = cbase + ni * 16 + l15;
                    if (row == col) s = 0.0f;
                }
                // exp(0.5s) ~= 1 + s/2 + s^2/8 + s^3/48  (|err| <= 0.0026 s^4)
                float p = fmaf(s, 0.02083333333f, 0.125f);
                p = fmaf(s, p, 0.5f);
                p = fmaf(s, p, 1.0f);
                if (r & 1) { aS1 += s; aN1 = fmaf(p, s, aN1); }
                else       { aS0 += s; aN0 = fmaf(p, s, aN0); }
            }
        }
    }
    float aS = aS0 + aS1, aN = aN0 + aN1;

    // ---- block reduction ----
    #pragma unroll
    for (int off = 32; off; off >>= 1) {
        aS += __shfl_down(aS, off, 64);
        aN += __shfl_down(aN, off, 64);
    }
    if (lane == 0) { red[wave * 2] = aS; red[wave * 2 + 1] = aN; }
    __syncthreads();
    if (t == 0) {
        float S = 0.0f, N = 0.0f;
        #pragma unroll
        for (int w = 0; w < 8; ++w) { S += red[w * 2]; N += red[w * 2 + 1]; }
        const float w = diag ? 1.0f : 2.0f;
        // neg_loss contribution: N/B ; regularization: GAMMA * S
        atomicAdd(&negacc[(blockIdx.x * 2 + blockIdx.y) & (NACC - 1)],
                  w * (N * (1.0f / (float)BHALF) + 0.5f * S));
    }
}

// ---- Kernel 3: final sum (64 neg slots + 256 prep partials) ----
__global__ void finish_kernel(const float* __restrict__ negacc,
                              const float* __restrict__ part,
                              float* __restrict__ out) {
    const int lane = threadIdx.x & 63;
    float v = negacc[lane];
    float pp = part[lane] + part[lane + 64] + part[lane + 128] + part[lane + 192];
    v = fmaf(pp, 1.0f / (float)BHALF, v);
    #pragma unroll
    for (int off = 32; off; off >>= 1) v += __shfl_down(v, off, 64);
    if (lane == 0) out[0] = v;
}

extern "C" void kernel_launch(void* const* d_in, const int* in_sizes, int n_in,
                              void* d_out, int out_size, void* d_ws, size_t ws_size,
                              hipStream_t stream) {
    const float* f = (const float*)d_in[0];
    float* out = (float*)d_out;
    unsigned short* xbf = (unsigned short*)d_ws;
    float* xx = (float*)((char*)d_ws + (size_t)NROWS * D * sizeof(unsigned short));
    float* negacc = xx + NROWS;
    float* part = negacc + NACC;

    prep_pos_kernel<<<NPART, 512, 0, stream>>>(f, xbf, xx, part, negacc);
    neg_kernel<<<dim3(NPAIRS, 2), 512, 0, stream>>>(xbf, xx, negacc);
    finish_kernel<<<1, 64, 0, stream>>>(negacc, part, out);
}